// Round 1
// baseline (1061.266 us; speedup 1.0000x reference)
//
#include <hip/hip_runtime.h>
#include <hip/hip_bf16.h>

// FlashAttention fwd: B=4, H=12, S=4096, D=64, fp32 in/out.
// Reproduces the reference's per-tile extra cur_scale factor exactly:
// TILE=128 k-tiles processed sequentially 0..31 with per-row running max.

#define S_LEN 4096
#define HD    64
#define QTILE 128
#define KTILE 128
#define NKT   (S_LEN / KTILE)   // 32
#define WAVES 4

#define KSTR 72                  // K_lds row stride (bf16 elems): 144B -> 2-way bank alias (free)
#define PSTR 136                 // P_lds row stride: 272B -> 2-way alias
#define VSTR 136                 // V_t row stride
#define PWAVE   (32 * PSTR)      // 4352 u16 per wave
#define VT_OFF  (WAVES * PWAVE)  // 17408 u16 (= 34816 B; K region [128][72]=18432 B aliases here)
#define SMEM_U16 (VT_OFF + HD * VSTR)  // 26112 u16 = 52224 B

typedef __attribute__((ext_vector_type(8))) short bf16x8;
typedef __attribute__((ext_vector_type(4))) float f32x4;

__device__ __forceinline__ unsigned short f2bf(float f) {
    unsigned int u = __builtin_bit_cast(unsigned int, f);
    u += 0x7FFFu + ((u >> 16) & 1u);           // RNE
    return (unsigned short)(u >> 16);
}

__device__ __forceinline__ bf16x8 cvt8(float4 a, float4 b, float s) {
    bf16x8 f;
    f[0] = (short)f2bf(a.x * s); f[1] = (short)f2bf(a.y * s);
    f[2] = (short)f2bf(a.z * s); f[3] = (short)f2bf(a.w * s);
    f[4] = (short)f2bf(b.x * s); f[5] = (short)f2bf(b.y * s);
    f[6] = (short)f2bf(b.z * s); f[7] = (short)f2bf(b.w * s);
    return f;
}

__global__ __launch_bounds__(256, 2)
void fattn_kernel(const float* __restrict__ Q,
                  const float* __restrict__ K,
                  const float* __restrict__ V,
                  float* __restrict__ O) {
    __shared__ unsigned short smem[SMEM_U16];

    const int t    = threadIdx.x;
    const int wave = t >> 6;
    const int lane = t & 63;
    const int m    = lane & 15;     // A-frag row / C-frag col
    const int quad = lane >> 4;     // 0..3

    const int qblk = blockIdx.x;    // 0..31
    const int head = blockIdx.y;    // 0..47
    const size_t hbase = (size_t)head * S_LEN * HD;

    unsigned short* const Kl = smem;                   // [128][KSTR], aliases P region
    unsigned short* const Pw = smem + wave * PWAVE;    // per-wave [32][PSTR]
    unsigned short* const Vt = smem + VT_OFF;          // [64][VSTR] (V transposed)

    // ---- Q fragments (A-layout), 0.125 scale folded in (exact pow2) ----
    bf16x8 qf[2][2];
    #pragma unroll
    for (int rt = 0; rt < 2; ++rt) {
        int row = qblk * QTILE + wave * 32 + rt * 16 + m;
        const float* qp = Q + hbase + (size_t)row * HD + quad * 8;
        #pragma unroll
        for (int kd = 0; kd < 2; ++kd) {
            const float4* p4 = reinterpret_cast<const float4*>(qp + kd * 32);
            qf[rt][kd] = cvt8(p4[0], p4[1], 0.125f);
        }
    }

    f32x4 oacc[2][4];
    float mrow[2][4], lrow[2][4];
    #pragma unroll
    for (int rt = 0; rt < 2; ++rt) {
        #pragma unroll
        for (int ct = 0; ct < 4; ++ct) { oacc[rt][ct] = (f32x4){0.f,0.f,0.f,0.f}; }
        #pragma unroll
        for (int r = 0; r < 4; ++r) { mrow[rt][r] = -INFINITY; lrow[rt][r] = 0.f; }
    }

    const int r0 = t >> 3;          // 0..31
    const int c0 = (t & 7) * 8;     // 0..56

    for (int kt = 0; kt < NKT; ++kt) {
        __syncthreads();            // prior iter's P/Vt reads finished

        // ---- stage K -> Kl [key][d] (bf16) ----
        #pragma unroll
        for (int i = 0; i < 4; ++i) {
            int r = r0 + i * 32;
            const float4* p4 = reinterpret_cast<const float4*>(
                K + hbase + (size_t)(kt * KTILE + r) * HD + c0);
            *reinterpret_cast<bf16x8*>(&Kl[r * KSTR + c0]) = cvt8(p4[0], p4[1], 1.0f);
        }
        // ---- stage V -> Vt [d][key] (bf16, transposed; j-rotation spreads banks) ----
        #pragma unroll
        for (int i = 0; i < 4; ++i) {
            int key = r0 + i * 32;
            const float4* p4 = reinterpret_cast<const float4*>(
                V + hbase + (size_t)(kt * KTILE + key) * HD + c0);
            float4 a = p4[0], b = p4[1];
            unsigned short bb[8] = { f2bf(a.x), f2bf(a.y), f2bf(a.z), f2bf(a.w),
                                     f2bf(b.x), f2bf(b.y), f2bf(b.z), f2bf(b.w) };
            #pragma unroll
            for (int jj = 0; jj < 8; ++jj) {
                int j = (jj + key) & 7;
                Vt[(c0 + j) * VSTR + key] = bb[j];
            }
        }
        __syncthreads();            // staging visible

        // ---- S = Q K^T  (scores already scaled via Q) ----
        f32x4 sacc[2][8];
        #pragma unroll
        for (int rt = 0; rt < 2; ++rt)
            #pragma unroll
            for (int c = 0; c < 8; ++c) sacc[rt][c] = (f32x4){0.f,0.f,0.f,0.f};

        #pragma unroll
        for (int kd = 0; kd < 2; ++kd) {
            #pragma unroll
            for (int c = 0; c < 8; ++c) {
                bf16x8 bf = *reinterpret_cast<const bf16x8*>(
                    &Kl[(c * 16 + m) * KSTR + kd * 32 + quad * 8]);
                #pragma unroll
                for (int rt = 0; rt < 2; ++rt)
                    sacc[rt][c] = __builtin_amdgcn_mfma_f32_16x16x32_bf16(
                        qf[rt][kd], bf, sacc[rt][c], 0, 0, 0);
            }
        }
        __syncthreads();            // all waves done reading Kl (region becomes P)

        // ---- online softmax (reference semantics, incl. extra cur_scale) ----
        #pragma unroll
        for (int rt = 0; rt < 2; ++rt) {
            #pragma unroll
            for (int reg = 0; reg < 4; ++reg) {
                float cm = sacc[rt][0][reg];
                #pragma unroll
                for (int c = 1; c < 8; ++c) cm = fmaxf(cm, sacc[rt][c][reg]);
                #pragma unroll
                for (int msk = 1; msk <= 8; msk <<= 1)
                    cm = fmaxf(cm, __shfl_xor(cm, msk, 64));

                float mo  = mrow[rt][reg];
                float mn  = fmaxf(mo, cm);
                float osc = __expf(mo - mn);   // exp(-inf)=0 on first tile
                float csc = __expf(cm - mn);   // the reference's extra factor
                mrow[rt][reg] = mn;

                #pragma unroll
                for (int ct = 0; ct < 4; ++ct) oacc[rt][ct][reg] *= osc;

                float rs = 0.f;
                const int prow = (rt * 16 + quad * 4 + reg) * PSTR;
                #pragma unroll
                for (int c = 0; c < 8; ++c) {
                    float p = __expf(sacc[rt][c][reg] - mn) * csc;
                    rs += p;
                    Pw[prow + c * 16 + m] = f2bf(p);
                }
                #pragma unroll
                for (int msk = 1; msk <= 8; msk <<= 1)
                    rs += __shfl_xor(rs, msk, 64);
                lrow[rt][reg] = lrow[rt][reg] * osc + rs;
            }
        }
        __syncthreads();            // P writes committed (safe same-wave RAW too)

        // ---- O += P' V ----
        #pragma unroll
        for (int kc = 0; kc < 4; ++kc) {
            bf16x8 af[2];
            #pragma unroll
            for (int rt = 0; rt < 2; ++rt)
                af[rt] = *reinterpret_cast<const bf16x8*>(
                    &Pw[(rt * 16 + m) * PSTR + kc * 32 + quad * 8]);
            #pragma unroll
            for (int ct = 0; ct < 4; ++ct) {
                bf16x8 vf = *reinterpret_cast<const bf16x8*>(
                    &Vt[(ct * 16 + m) * VSTR + kc * 32 + quad * 8]);
                #pragma unroll
                for (int rt = 0; rt < 2; ++rt)
                    oacc[rt][ct] = __builtin_amdgcn_mfma_f32_16x16x32_bf16(
                        af[rt], vf, oacc[rt][ct], 0, 0, 0);
            }
        }
    }

    // ---- epilogue: out = O / l ----
    #pragma unroll
    for (int rt = 0; rt < 2; ++rt) {
        #pragma unroll
        for (int reg = 0; reg < 4; ++reg) {
            int row = qblk * QTILE + wave * 32 + rt * 16 + quad * 4 + reg;
            float inv = 1.0f / lrow[rt][reg];
            float* op = O + hbase + (size_t)row * HD;
            #pragma unroll
            for (int ct = 0; ct < 4; ++ct)
                op[ct * 16 + m] = oacc[rt][ct][reg] * inv;
        }
    }
}

extern "C" void kernel_launch(void* const* d_in, const int* in_sizes, int n_in,
                              void* d_out, int out_size, void* d_ws, size_t ws_size,
                              hipStream_t stream) {
    (void)in_sizes; (void)n_in; (void)d_ws; (void)ws_size; (void)out_size;
    const float* Q = (const float*)d_in[0];
    const float* K = (const float*)d_in[1];
    const float* V = (const float*)d_in[2];
    float* O = (float*)d_out;
    dim3 grid(S_LEN / QTILE, 4 * 12);   // 32 q-tiles x 48 heads
    fattn_kernel<<<grid, 256, 0, stream>>>(Q, K, V, O);
}

// Round 2
// 489.186 us; speedup vs baseline: 2.1695x; 2.1695x over previous
//
#include <hip/hip_runtime.h>
#include <hip/hip_bf16.h>

// FlashAttention fwd: B=4,H=12,S=4096,D=64 fp32. Reference semantics incl. the
// extra cur_scale factor, folded as p = exp(s + cm - 2*mn).
// S computed TRANSPOSED (S^T = K.Q^T) so P stays in registers: the C-layout of
// S^T matches the PV B-operand layout under the k-slot permutation
// key = kc*32 + (j>>2)*16 + quad*4 + (j&3), absorbed into the Vt read address.

#define S_LEN 4096
#define HD    64
#define QTILE 128
#define KTILE 128
#define NKT   (S_LEN / KTILE)      // 32

#define KSTR  72                    // u16 stride of K_lds rows
#define VSTR  136                   // u16 stride of Vt rows
#define VT_OFF (128 * KSTR)         // 9216 u16
#define SMEM_U16 (VT_OFF + HD * VSTR)  // 17920 u16 = 35840 B
#define OSTR  68                    // epilogue float stride

typedef __attribute__((ext_vector_type(8))) short bf16x8;
typedef __attribute__((ext_vector_type(4))) short bf16x4;
typedef __attribute__((ext_vector_type(4))) float f32x4;

// round-half-up f32->bf16 pair, packed into one u32 via v_perm_b32
__device__ __forceinline__ unsigned int pk2(float f0, float f1) {
    unsigned int u0 = __builtin_bit_cast(unsigned int, f0) + 0x8000u;
    unsigned int u1 = __builtin_bit_cast(unsigned int, f1) + 0x8000u;
    return __builtin_amdgcn_perm(u1, u0, 0x07060302u);  // (hi16(u1)<<16)|hi16(u0)
}

__global__ __launch_bounds__(256, 3)
void fattn_kernel(const float* __restrict__ Q,
                  const float* __restrict__ K,
                  const float* __restrict__ V,
                  float* __restrict__ O) {
    __shared__ __align__(16) unsigned short smem[SMEM_U16];

    const int t    = threadIdx.x;
    const int wave = t >> 6;
    const int lane = t & 63;
    const int m    = lane & 15;
    const int quad = lane >> 4;

    const int qblk = blockIdx.x;
    const int head = blockIdx.y;
    const size_t hbase = (size_t)head * S_LEN * HD;

    unsigned short* const Kl = smem;
    unsigned short* const Vt = smem + VT_OFF;

    // ---- Q B-frags (scale 0.125 folded; B-layout: n=lane&15, k=quad*8+j) ----
    bf16x8 qf[2][2];
    #pragma unroll
    for (int rt = 0; rt < 2; ++rt) {
        const float* qp = Q + hbase +
            (size_t)(qblk * QTILE + wave * 32 + rt * 16 + m) * HD + quad * 8;
        #pragma unroll
        for (int kd = 0; kd < 2; ++kd) {
            float4 a = *(const float4*)(qp + kd * 32);
            float4 b = *(const float4*)(qp + kd * 32 + 4);
            union { unsigned int u[4]; bf16x8 v; } cv;
            cv.u[0] = pk2(a.x * 0.125f, a.y * 0.125f);
            cv.u[1] = pk2(a.z * 0.125f, a.w * 0.125f);
            cv.u[2] = pk2(b.x * 0.125f, b.y * 0.125f);
            cv.u[3] = pk2(b.z * 0.125f, b.w * 0.125f);
            qf[rt][kd] = cv.v;
        }
    }

    // accumulators / state
    f32x4 oacc[4][2];               // O^T[d-tile][rt], C-layout
    float mrow[2] = {-INFINITY, -INFINITY};
    float lrow[2] = {0.f, 0.f};
    #pragma unroll
    for (int dt = 0; dt < 4; ++dt)
        #pragma unroll
        for (int rt = 0; rt < 2; ++rt) oacc[dt][rt] = (f32x4){0.f,0.f,0.f,0.f};

    // staging maps
    const int r0k = t >> 3;                        // K: row 0..31 (+32i)
    const int c0k = (t & 7) * 8;                   // K: global col
    const int chk = ((t & 7) + ((t >> 3) & 7)) & 7;// K: swizzled chunk
    const int vkey = t & 127;                      // V: key per thread
    const int vdb  = (t >> 7) * 32;                // V: d-base 0/32
    unsigned short* const vwp = &Vt[vdb * VSTR + vkey];

    // ---- initial V prefetch (tile 0) ----
    float4 va[4][2];
    {
        const float* vp = V + hbase + (size_t)vkey * HD + vdb;
        #pragma unroll
        for (int i = 0; i < 4; ++i) {
            va[i][0] = *(const float4*)(vp + i * 8);
            va[i][1] = *(const float4*)(vp + i * 8 + 4);
        }
    }

    for (int kt = 0; kt < NKT; ++kt) {
        __syncthreads();   // previous tile's LDS reads done

        // ---- write prefetched V regs -> Vt (transposed; conflict-free) ----
        #pragma unroll
        for (int i = 0; i < 4; ++i) {
            #pragma unroll
            for (int j = 0; j < 8; ++j) {
                float f = ((const float*)&va[i][j >> 2])[j & 3];
                unsigned int u = __builtin_bit_cast(unsigned int, f) + 0x8000u;
                vwp[(i * 8 + j) * VSTR] = (unsigned short)(u >> 16);
            }
        }
        // ---- stage K tile kt (row-swizzled chunks) ----
        {
            const float* kp = K + hbase + (size_t)(kt * KTILE + r0k) * HD + c0k;
            #pragma unroll
            for (int i = 0; i < 4; ++i) {
                float4 a = *(const float4*)(kp + i * 32 * HD);
                float4 b = *(const float4*)(kp + i * 32 * HD + 4);
                union { unsigned int u[4]; bf16x4 v[2]; } cv;
                cv.u[0] = pk2(a.x, a.y); cv.u[1] = pk2(a.z, a.w);
                cv.u[2] = pk2(b.x, b.y); cv.u[3] = pk2(b.z, b.w);
                *(bf16x8*)&Kl[(r0k + i * 32) * KSTR + chk * 8] =
                    *(bf16x8*)&cv.u[0];
            }
        }
        __syncthreads();   // staging visible

        // ---- prefetch next tile's V into regs (hidden behind compute) ----
        {
            int nk = (kt + 1 < NKT) ? kt + 1 : 0;
            const float* vp = V + hbase + (size_t)(nk * KTILE + vkey) * HD + vdb;
            #pragma unroll
            for (int i = 0; i < 4; ++i) {
                va[i][0] = *(const float4*)(vp + i * 8);
                va[i][1] = *(const float4*)(vp + i * 8 + 4);
            }
        }

        // ---- S^T = K.Q^T : sacc[k8][rt], row=key(16k8+quad*4+reg), col=qrow ----
        f32x4 sacc[8][2];
        #pragma unroll
        for (int k8 = 0; k8 < 8; ++k8)
            #pragma unroll
            for (int rt = 0; rt < 2; ++rt) sacc[k8][rt] = (f32x4){0.f,0.f,0.f,0.f};

        #pragma unroll
        for (int kd = 0; kd < 2; ++kd) {
            const int coff = (((kd << 2) + quad + m) & 7) << 3;  // unswizzle
            #pragma unroll
            for (int k8 = 0; k8 < 8; ++k8) {
                bf16x8 kf = *(const bf16x8*)&Kl[(k8 * 16 + m) * KSTR + coff];
                sacc[k8][0] = __builtin_amdgcn_mfma_f32_16x16x32_bf16(
                    kf, qf[0][kd], sacc[k8][0], 0, 0, 0);
                sacc[k8][1] = __builtin_amdgcn_mfma_f32_16x16x32_bf16(
                    kf, qf[1][kd], sacc[k8][1], 0, 0, 0);
            }
        }

        // ---- online softmax in registers; P packed to bf16 pairs ----
        unsigned int pkv[8][2][2];
        #pragma unroll
        for (int rt = 0; rt < 2; ++rt) {
            float cm = sacc[0][rt][0];
            #pragma unroll
            for (int k8 = 0; k8 < 8; ++k8)
                #pragma unroll
                for (int r = 0; r < 4; ++r)
                    cm = fmaxf(cm, sacc[k8][rt][r]);
            cm = fmaxf(cm, __shfl_xor(cm, 16, 64));
            cm = fmaxf(cm, __shfl_xor(cm, 32, 64));

            float mo  = mrow[rt];
            float mn  = fmaxf(mo, cm);
            float osc = __expf(mo - mn);          // exp(-inf)=0 first tile
            float bias = cm - mn - mn;            // p = exp(s + cm - 2mn)
            mrow[rt] = mn;

            #pragma unroll
            for (int dt = 0; dt < 4; ++dt) {
                oacc[dt][rt][0] *= osc; oacc[dt][rt][1] *= osc;
                oacc[dt][rt][2] *= osc; oacc[dt][rt][3] *= osc;
            }

            float rs = 0.f;
            #pragma unroll
            for (int k8 = 0; k8 < 8; ++k8) {
                float p0 = __expf(sacc[k8][rt][0] + bias);
                float p1 = __expf(sacc[k8][rt][1] + bias);
                float p2 = __expf(sacc[k8][rt][2] + bias);
                float p3 = __expf(sacc[k8][rt][3] + bias);
                rs += (p0 + p1) + (p2 + p3);
                pkv[k8][rt][0] = pk2(p0, p1);
                pkv[k8][rt][1] = pk2(p2, p3);
            }
            rs += __shfl_xor(rs, 16, 64);
            rs += __shfl_xor(rs, 32, 64);
            lrow[rt] = lrow[rt] * osc + rs;
        }

        // ---- O^T += V^T.P^T  (P from registers; permuted key order) ----
        #pragma unroll
        for (int kc = 0; kc < 4; ++kc) {
            bf16x8 pf[2];
            #pragma unroll
            for (int rt = 0; rt < 2; ++rt) {
                union { unsigned int u[4]; bf16x8 v; } cv;
                cv.u[0] = pkv[2 * kc][rt][0];
                cv.u[1] = pkv[2 * kc][rt][1];
                cv.u[2] = pkv[2 * kc + 1][rt][0];
                cv.u[3] = pkv[2 * kc + 1][rt][1];
                pf[rt] = cv.v;
            }
            #pragma unroll
            for (int dt = 0; dt < 4; ++dt) {
                const unsigned short* vp0 =
                    &Vt[(dt * 16 + m) * VSTR + kc * 32 + quad * 4];
                bf16x4 a = *(const bf16x4*)vp0;
                bf16x4 b = *(const bf16x4*)(vp0 + 16);
                bf16x8 vf;
                vf[0]=a[0]; vf[1]=a[1]; vf[2]=a[2]; vf[3]=a[3];
                vf[4]=b[0]; vf[5]=b[1]; vf[6]=b[2]; vf[7]=b[3];
                oacc[dt][0] = __builtin_amdgcn_mfma_f32_16x16x32_bf16(
                    vf, pf[0], oacc[dt][0], 0, 0, 0);
                oacc[dt][1] = __builtin_amdgcn_mfma_f32_16x16x32_bf16(
                    vf, pf[1], oacc[dt][1], 0, 0, 0);
            }
        }
    }

    // ---- epilogue: O^T/l -> LDS transpose -> coalesced float4 stores ----
    __syncthreads();
    float* Ol = (float*)smem;
    #pragma unroll
    for (int rt = 0; rt < 2; ++rt) {
        float inv = 1.0f / lrow[rt];
        #pragma unroll
        for (int dt = 0; dt < 4; ++dt)
            #pragma unroll
            for (int r = 0; r < 4; ++r)
                Ol[(wave * 32 + rt * 16 + m) * OSTR + dt * 16 + quad * 4 + r] =
                    oacc[dt][rt][r] * inv;
    }
    __syncthreads();
    const size_t obase = hbase + (size_t)(qblk * QTILE) * HD;
    #pragma unroll
    for (int s = 0; s < 8; ++s) {
        int row = s * 16 + (t >> 4);
        int col = (t & 15) * 4;
        *(float4*)&O[obase + (size_t)row * HD + col] =
            *(const float4*)&Ol[row * OSTR + col];
    }
}

extern "C" void kernel_launch(void* const* d_in, const int* in_sizes, int n_in,
                              void* d_out, int out_size, void* d_ws, size_t ws_size,
                              hipStream_t stream) {
    (void)in_sizes; (void)n_in; (void)d_ws; (void)ws_size; (void)out_size;
    const float* Q = (const float*)d_in[0];
    const float* K = (const float*)d_in[1];
    const float* V = (const float*)d_in[2];
    float* O = (float*)d_out;
    dim3 grid(S_LEN / QTILE, 4 * 12);
    fattn_kernel<<<grid, 256, 0, stream>>>(Q, K, V, O);
}